// Round 1
// baseline (320.820 us; speedup 1.0000x reference)
//
#include <hip/hip_runtime.h>
#include <stdint.h>

// DiffAttention fwd: B=2, N=2048, EMB=1024, H=8 heads, 2 sub-heads of HD=64 each.
// Pipeline: cvt(f32->bf16) -> lambda -> fused QKV NT-GEMM (V written transposed)
//           -> flash attention (dual online softmax, diff-combine) -> out GEMM.

typedef __attribute__((ext_vector_type(8))) __bf16 bf16x8;
typedef __attribute__((ext_vector_type(4))) float f32x4;
typedef __attribute__((ext_vector_type(8))) unsigned short u16x8;
typedef __attribute__((ext_vector_type(4))) unsigned short u16x4;
typedef unsigned short u16;
typedef unsigned int u32;

#define EMB 1024
#define NSEQ 2048
#define NBATCH 2
#define NHEAD 8
#define MROWS (NBATCH*NSEQ)   // 4096

__device__ __forceinline__ u16 f2bf(float f){
  u32 x = __builtin_bit_cast(u32, f);
  return (u16)((x + 0x7fffu + ((x >> 16) & 1u)) >> 16);   // RNE (inputs are finite)
}

__device__ __forceinline__ bf16x8 ld8(const u16* p){
  return __builtin_bit_cast(bf16x8, *(const u16x8*)p);
}

// async global->LDS, 16B per lane; LDS dest = wave-uniform base + lane*16
__device__ __forceinline__ void glds16(const u16* g, u16* l){
  __builtin_amdgcn_global_load_lds(
      (const __attribute__((address_space(1))) u32*)g,
      (__attribute__((address_space(3))) u32*)l, 16, 0, 0);
}

// ---------------- f32 -> bf16 conversion of all operands ----------------
__global__ void cvt_k(const float* __restrict__ q, const float* __restrict__ k,
                      const float* __restrict__ v, const float* __restrict__ Wq,
                      const float* __restrict__ Wk, const float* __restrict__ Wv,
                      const float* __restrict__ Wo,
                      u16* qb, u16* kb, u16* vb, u16* Wqb, u16* Wkb, u16* Wvb, u16* Wob)
{
  const int NQ4 = (NBATCH*NSEQ*EMB)/4;   // 1048576 float4 per q/k/v
  const int NW4 = (EMB*EMB)/4;           // 262144 per W
  const int total = 3*NQ4 + 4*NW4;
  for (int i = blockIdx.x*blockDim.x + threadIdx.x; i < total; i += gridDim.x*blockDim.x){
    const float* src; u16* dst; int off;
    if (i < 3*NQ4){
      int t = i / NQ4; off = i - t*NQ4;
      src = t==0 ? q : (t==1 ? k : v);
      dst = t==0 ? qb : (t==1 ? kb : vb);
    } else {
      int j = i - 3*NQ4;
      int t = j / NW4; off = j - t*NW4;
      src = t==0 ? Wq : (t==1 ? Wk : (t==2 ? Wv : Wo));
      dst = t==0 ? Wqb : (t==1 ? Wkb : (t==2 ? Wvb : Wob));
    }
    f32x4 f = *((const f32x4*)src + off);
    u16x4 u; u[0]=f2bf(f[0]); u[1]=f2bf(f[1]); u[2]=f2bf(f[2]); u[3]=f2bf(f[3]);
    *((u16x4*)dst + off) = u;
  }
}

// ---------------- lambda scalar ----------------
__global__ void lambda_k(const float* __restrict__ lq1, const float* __restrict__ lk1,
                         const float* __restrict__ lq2, const float* __restrict__ lk2,
                         float* lam)
{
  int l = threadIdx.x;                 // 64 threads
  float p1 = lq1[l]*lk1[l];
  float p2 = lq2[l]*lk2[l];
  #pragma unroll
  for (int m=1; m<64; m<<=1){ p1 += __shfl_xor(p1, m, 64); p2 += __shfl_xor(p2, m, 64); }
  if (l==0) lam[0] = __expf(p1) - __expf(p2) + 0.8f;
}

// ---------------- NT GEMM core: Y[m,n] = sum_k A[m,k]*W[n,k] + bias[n] ----------------
// 128x128 tile, BK=32, 4 waves (each 64x64 = 4x4 frags of 16x16x32 MFMA),
// global_load_lds width-16 staging (m97 structure).
// mode 0: bf16 row-major out (Ybf); mode 1: bf16 transposed-per-head out (Yvt, V path);
// mode 2: f32 row-major out (Yf).
__device__ __forceinline__ void gemm_core(
    const u16* __restrict__ A, const u16* __restrict__ W, const float* __restrict__ bias,
    u16* __restrict__ Ybf, u16* __restrict__ Yvt, float* __restrict__ Yf, int mode,
    u16* As, u16* Bs)
{
  const int tid = threadIdx.x, w = tid >> 6, l = tid & 63;
  const int l15 = l & 15, lg = l >> 4;
  const int m0 = blockIdx.y * 128, n0 = blockIdx.x * 128;
  const int wr = w >> 1, wc = w & 1;
  const int srow = w*16 + (l >> 2);    // staging row within a 64-row half
  const int skel = (l & 3) * 8;        // staging k-elem offset (16B)

  f32x4 acc[4][4] = {};

  for (int kt = 0; kt < EMB/32; ++kt){
    const int kb = kt*32 + skel;
    glds16(A + (size_t)(m0 + srow)*EMB + kb,      As + w*512);
    glds16(A + (size_t)(m0 + 64 + srow)*EMB + kb, As + 2048 + w*512);
    glds16(W + (size_t)(n0 + srow)*EMB + kb,      Bs + w*512);
    glds16(W + (size_t)(n0 + 64 + srow)*EMB + kb, Bs + 2048 + w*512);
    __syncthreads();   // drains vmcnt for global_load_lds

    bf16x8 af[4], bfr[4];
    #pragma unroll
    for (int mi=0; mi<4; ++mi) af[mi]  = ld8(As + (wr*64 + mi*16 + l15)*32 + lg*8);
    #pragma unroll
    for (int ni=0; ni<4; ++ni) bfr[ni] = ld8(Bs + (wc*64 + ni*16 + l15)*32 + lg*8);
    #pragma unroll
    for (int mi=0; mi<4; ++mi)
      #pragma unroll
      for (int ni=0; ni<4; ++ni)
        acc[mi][ni] = __builtin_amdgcn_mfma_f32_16x16x32_bf16(af[mi], bfr[ni], acc[mi][ni], 0,0,0);
    __syncthreads();
  }

  #pragma unroll
  for (int mi=0; mi<4; ++mi){
    const int mr = m0 + wr*64 + mi*16 + lg*4;   // + i rows, D: row=(l>>4)*4+i, col=l&15
    #pragma unroll
    for (int ni=0; ni<4; ++ni){
      const int nc = n0 + wc*64 + ni*16 + l15;
      const float bv = bias[nc];
      if (mode == 0){
        #pragma unroll
        for (int i=0;i<4;++i) Ybf[(size_t)(mr+i)*EMB + nc] = f2bf(acc[mi][ni][i] + bv);
      } else if (mode == 1){
        const int h = nc >> 7, vd = nc & 127, bb = mr >> 11, t = mr & 2047;
        u16x4 pk;
        #pragma unroll
        for (int i=0;i<4;++i) pk[i] = f2bf(acc[mi][ni][i] + bv);
        *(u16x4*)(Yvt + ((size_t)((bb*NHEAD + h)*128 + vd))*NSEQ + t) = pk;
      } else {
        #pragma unroll
        for (int i=0;i<4;++i) Yf[(size_t)(mr+i)*EMB + nc] = acc[mi][ni][i] + bv;
      }
    }
  }
}

__global__ __launch_bounds__(256) void gemm_qkv(
    const u16* qb, const u16* kb, const u16* vb,
    const u16* Wqb, const u16* Wkb, const u16* Wvb,
    const float* bq, const float* bk, const float* bv,
    u16* Qp, u16* Kp, u16* Vt)
{
  __shared__ __align__(16) u16 As[4096], Bs[4096];
  const int z = blockIdx.z;
  const u16* A = z==0 ? qb : (z==1 ? kb : vb);
  const u16* W = z==0 ? Wqb : (z==1 ? Wkb : Wvb);
  const float* bias = z==0 ? bq : (z==1 ? bk : bv);
  if (z < 2) gemm_core(A, W, bias, z==0 ? Qp : Kp, nullptr, nullptr, 0, As, Bs);
  else       gemm_core(A, W, bias, nullptr, Vt, nullptr, 1, As, Bs);
}

__global__ __launch_bounds__(256) void gemm_out_k(
    const u16* Xc, const u16* Wob, const float* bo, float* out)
{
  __shared__ __align__(16) u16 As[4096], Bs[4096];
  gemm_core(Xc, Wob, bo, nullptr, nullptr, out, 2, As, Bs);
}

// ---------------- differential flash attention ----------------
// grid: 512 blocks = (b,h) x 32 q-tiles; 4 waves/block, each wave = 16 q rows,
// both sub-heads. K/V frags direct from global (L2-resident), P via per-wave LDS.
__global__ __launch_bounds__(256) void attn_k(
    const u16* __restrict__ Qp, const u16* __restrict__ Kp,
    const u16* __restrict__ Vt, const float* __restrict__ lamp,
    u16* __restrict__ Xc)
{
  __shared__ __align__(16) u16 Plds[4][2][16*72];  // per-wave, per-subhead P buffers
  const int tid = threadIdx.x, w = tid >> 6, l = tid & 63;
  const int l15 = l & 15, lg = l >> 4;
  const int bid = blockIdx.x;
  const int qt = bid & 31, bh = bid >> 5;
  const int b = bh >> 3, h = bh & 7;
  const int q0 = qt*64 + w*16;
  const float lam = lamp[0];
  const float C = 0.125f * 1.4426950408889634f;    // scale * log2(e)

  bf16x8 qa[2][2];
  #pragma unroll
  for (int s=0; s<2; ++s)
    #pragma unroll
    for (int ks=0; ks<2; ++ks)
      qa[s][ks] = ld8(Qp + (size_t)(b*NSEQ + q0 + l15)*EMB + (2*h+s)*64 + ks*32 + lg*8);

  f32x4 acc[2][8] = {};
  float mrow[2][4], lsum[2][4];
  #pragma unroll
  for (int s=0;s<2;++s)
    #pragma unroll
    for (int i=0;i<4;++i){ mrow[s][i] = -1e30f; lsum[s][i] = 0.f; }

  u16* pb0 = &Plds[w][0][0];
  u16* pb1 = &Plds[w][1][0];

  for (int kt = 0; kt < NSEQ/64; ++kt){
    #pragma unroll
    for (int s=0; s<2; ++s){
      u16* pb = s ? pb1 : pb0;
      f32x4 st[4] = {};
      #pragma unroll
      for (int nt=0; nt<4; ++nt)
        #pragma unroll
        for (int ks=0; ks<2; ++ks){
          bf16x8 kf = ld8(Kp + (size_t)(b*NSEQ + kt*64 + nt*16 + l15)*EMB
                              + (2*h+s)*64 + ks*32 + lg*8);
          st[nt] = __builtin_amdgcn_mfma_f32_16x16x32_bf16(qa[s][ks], kf, st[nt], 0,0,0);
        }
      // online softmax: D layout col=key=l&15(+16nt), row=q=lg*4+i
      float tm[4];
      #pragma unroll
      for (int i=0;i<4;++i) tm[i] = fmaxf(fmaxf(st[0][i], st[1][i]), fmaxf(st[2][i], st[3][i]));
      #pragma unroll
      for (int m=1; m<16; m<<=1)
        #pragma unroll
        for (int i=0;i<4;++i) tm[i] = fmaxf(tm[i], __shfl_xor(tm[i], m, 64));
      float al[4];
      #pragma unroll
      for (int i=0;i<4;++i){
        float mn = fmaxf(mrow[s][i], tm[i]);
        al[i] = exp2f((mrow[s][i] - mn)*C);
        mrow[s][i] = mn;
      }
      float ts[4] = {0.f,0.f,0.f,0.f};
      #pragma unroll
      for (int nt=0; nt<4; ++nt)
        #pragma unroll
        for (int i=0;i<4;++i){
          float p = exp2f((st[nt][i] - mrow[s][i])*C);
          st[nt][i] = p; ts[i] += p;
        }
      #pragma unroll
      for (int m=1; m<16; m<<=1)
        #pragma unroll
        for (int i=0;i<4;++i) ts[i] += __shfl_xor(ts[i], m, 64);
      #pragma unroll
      for (int i=0;i<4;++i) lsum[s][i] = lsum[s][i]*al[i] + ts[i];
      #pragma unroll
      for (int vt=0; vt<8; ++vt)
        #pragma unroll
        for (int i=0;i<4;++i) acc[s][vt][i] *= al[i];
      // P -> LDS (bf16), row=q, col=key, stride 72 (pad: conflict-free b128 reads)
      #pragma unroll
      for (int nt=0; nt<4; ++nt)
        #pragma unroll
        for (int i=0;i<4;++i)
          pb[(lg*4 + i)*72 + nt*16 + l15] = f2bf(st[nt][i]);
    }
    // read P as A-frags: lane: row=q=l&15, k=key=ks*32+lg*8..+7
    bf16x8 pa0[2], pa1[2];
    #pragma unroll
    for (int ks=0; ks<2; ++ks){
      pa0[ks] = ld8(pb0 + l15*72 + ks*32 + lg*8);
      pa1[ks] = ld8(pb1 + l15*72 + ks*32 + lg*8);
    }
    // PV: B-frag from Vt (V transposed: [vd][t]) — contiguous 16B per lane
    const u16* vbase = Vt + (size_t)((b*NHEAD + h)*128)*NSEQ + kt*64;
    #pragma unroll
    for (int ks=0; ks<2; ++ks)
      #pragma unroll
      for (int vt=0; vt<8; ++vt){
        bf16x8 vf = ld8(vbase + (size_t)(vt*16 + l15)*NSEQ + ks*32 + lg*8);
        acc[0][vt] = __builtin_amdgcn_mfma_f32_16x16x32_bf16(pa0[ks], vf, acc[0][vt], 0,0,0);
        acc[1][vt] = __builtin_amdgcn_mfma_f32_16x16x32_bf16(pa1[ks], vf, acc[1][vt], 0,0,0);
      }
  }

  float i0[4], i1l[4];
  #pragma unroll
  for (int i=0;i<4;++i){ i0[i] = 1.f/lsum[0][i]; i1l[i] = lam/lsum[1][i]; }
  #pragma unroll
  for (int vt=0; vt<8; ++vt)
    #pragma unroll
    for (int i=0;i<4;++i){
      float v = acc[0][vt][i]*i0[i] - acc[1][vt][i]*i1l[i];
      Xc[(size_t)(b*NSEQ + q0 + lg*4 + i)*EMB + h*128 + vt*16 + l15] = f2bf(v);
    }
}

// ---------------- host launch ----------------
extern "C" void kernel_launch(void* const* d_in, const int* in_sizes, int n_in,
                              void* d_out, int out_size, void* d_ws, size_t ws_size,
                              hipStream_t stream)
{
  const float* q   = (const float*)d_in[0];
  const float* k   = (const float*)d_in[1];
  const float* v   = (const float*)d_in[2];
  const float* Wq  = (const float*)d_in[3];
  const float* bq  = (const float*)d_in[4];
  const float* Wk  = (const float*)d_in[5];
  const float* bk  = (const float*)d_in[6];
  const float* Wv  = (const float*)d_in[7];
  const float* bv  = (const float*)d_in[8];
  const float* Wo  = (const float*)d_in[9];
  const float* bo  = (const float*)d_in[10];
  const float* lq1 = (const float*)d_in[11];
  const float* lk1 = (const float*)d_in[12];
  const float* lq2 = (const float*)d_in[13];
  const float* lk2 = (const float*)d_in[14];

  const size_t NQ = (size_t)MROWS*EMB;   // 4194304
  const size_t NW = (size_t)EMB*EMB;     // 1048576
  u16* qb  = (u16*)d_ws;
  u16* kb  = qb + NQ;
  u16* vb  = kb + NQ;
  u16* Wqb = vb + NQ;
  u16* Wkb = Wqb + NW;
  u16* Wvb = Wkb + NW;
  u16* Wob = Wvb + NW;
  u16* Qp  = Wob + NW;
  u16* Kp  = Qp + NQ;
  u16* Vt  = Kp + NQ;
  u16* Xc  = Vt + NQ;
  float* lam = (float*)(Xc + NQ);

  cvt_k<<<2048, 256, 0, stream>>>(q, k, v, Wq, Wk, Wv, Wo,
                                  qb, kb, vb, Wqb, Wkb, Wvb, Wob);
  lambda_k<<<1, 64, 0, stream>>>(lq1, lk1, lq2, lk2, lam);
  gemm_qkv<<<dim3(EMB/128, MROWS/128, 3), 256, 0, stream>>>(
      qb, kb, vb, Wqb, Wkb, Wvb, bq, bk, bv, Qp, Kp, Vt);
  attn_k<<<dim3(NBATCH*NHEAD*(NSEQ/64)), 256, 0, stream>>>(Qp, Kp, Vt, lam, Xc);
  gemm_out_k<<<dim3(EMB/128, MROWS/128), 256, 0, stream>>>(Xc, Wob, bo, (float*)d_out);
}